// Round 5
// baseline (139.531 us; speedup 1.0000x reference)
//
#include <hip/hip_runtime.h>
#include <hip/hip_bf16.h>

// RelativeSemanticLoss via bf16 MFMA GEMM + fused softmax-NLL epilogue.
// R5: 32x32x16 MFMA (conflict-free pred LDS reads, half the DS ops),
// async global_load_lds double-buffering, 3 blocks/CU.

#define NUM_CLS 150
#define NT_TILES 5       // 5 x 32 = 160 padded classes
#define D_DIM   512
#define HW_DIM  65536
#define IGNORE_L 255

typedef __attribute__((ext_vector_type(8)))  short bf16x8;
typedef __attribute__((ext_vector_type(16))) float f32x16;
typedef __attribute__((ext_vector_type(4)))  unsigned int u32x4;

#define GLOAD16(gsrc, ldst) \
    __builtin_amdgcn_global_load_lds((const __attribute__((address_space(1))) void*)(gsrc), \
                                     (__attribute__((address_space(3))) void*)(ldst), 16, 0, 0)

static __device__ __forceinline__ short f2bf(float f) {
    __hip_bfloat16 h = __float2bfloat16(f);   // RNE
    return __builtin_bit_cast(short, h);
}

// Pack cls (150x512 fp32) -> bf16 32x32x16 B-fragments, lane-linear:
// packed[(s2*5+nt)*512 + l*8 + j] = bf16(cls[nt*32+(l&31)][s2*16+(l>>5)*8+j])
// s2 = 0..31 (K-steps of 16). Also zeroes ws accumulators.
__global__ void rsl_pack_cls(const float* __restrict__ cls,
                             unsigned short* __restrict__ packed,
                             double* __restrict__ ws_sum,
                             unsigned long long* __restrict__ ws_cnt)
{
    int t = blockIdx.x * 256 + threadIdx.x;      // 0 .. 32*5*64-1
    if (t == 0) { ws_sum[0] = 0.0; ws_cnt[0] = 0ull; }
    if (t >= 32 * NT_TILES * 64) return;
    int s2 = t / (NT_TILES * 64);
    int r  = t - s2 * (NT_TILES * 64);
    int nt = r >> 6;
    int l  = r & 63;
    int c  = nt * 32 + (l & 31);
    int k  = s2 * 16 + (l >> 5) * 8;
    unsigned short v[8];
#pragma unroll
    for (int j = 0; j < 8; ++j)
        v[j] = (c < NUM_CLS) ? (unsigned short)f2bf(cls[c * D_DIM + k + j]) : (unsigned short)0;
    u32x4 w;
#pragma unroll
    for (int q = 0; q < 4; ++q)
        w[q] = (unsigned int)v[2 * q] | ((unsigned int)v[2 * q + 1] << 16);
    *(u32x4*)(packed + (size_t)(s2 * NT_TILES + nt) * 512 + (size_t)l * 8) = w;
}

__global__ __launch_bounds__(256, 3)
void rsl_mfma(const float* __restrict__ pred,
              const unsigned short* __restrict__ packed,
              const int*   __restrict__ idx,
              const int*   __restrict__ lut,
              double* __restrict__ ws_sum,
              unsigned long long* __restrict__ ws_cnt)
{
    // LDS: pred tile [32 dims][128 px] fp32 16KB x2 + cls 10KB x2 = 52KB -> 3 blocks/CU
    __shared__ float          sP[2][32][128];
    __shared__ unsigned short sC[2][10][512];    // 10 = 2 k-steps x 5 nt

    const int lane = threadIdx.x & 63;
    const int wid  = threadIdx.x >> 6;
    const int col  = lane & 31;      // A-frag pixel row / C-D class col
    const int hi   = lane >> 5;      // k-half (A/B frags) / pixel-row offset (C/D)

    const int pixbase = blockIdx.x * 128;        // never straddles b (65536%128==0)
    const int b  = pixbase >> 16;
    const int p0 = pixbase & 0xFFFF;
    const float* pstage = pred + (size_t)b * D_DIM * HW_DIM
                        + (size_t)(lane >> 5) * HW_DIM + (p0 + (lane & 31) * 4);

    f32x16 acc[NT_TILES] = {};

    // ---- prologue: stage s=0 ----
#pragma unroll
    for (int tt = 0; tt < 4; ++tt) {
        const int t = wid * 4 + tt;              // dim-pair 0..15
        GLOAD16(pstage + (size_t)(2 * t) * HW_DIM, &sP[0][2 * t][0]);
    }
    for (int i = wid; i < 10; i += 4)
        GLOAD16(packed + (size_t)i * 512 + (size_t)lane * 8, &sC[0][i][0]);
    __syncthreads();

    for (int s = 0; s < 16; ++s) {
        const int cur = s & 1;
        // ---- stage s+1 (async DMA) ----
        if (s < 15) {
            const float* srcb = pstage + (size_t)((s + 1) * 32) * HW_DIM;
#pragma unroll
            for (int tt = 0; tt < 4; ++tt) {
                const int t = wid * 4 + tt;
                GLOAD16(srcb + (size_t)(2 * t) * HW_DIM, &sP[cur ^ 1][2 * t][0]);
            }
            const unsigned short* csrc = packed + (size_t)((s + 1) * 10) * 512 + (size_t)lane * 8;
            for (int i = wid; i < 10; i += 4)
                GLOAD16(csrc + (size_t)i * 512, &sC[cur ^ 1][i][0]);
        }

        // ---- compute: 2 K-steps of 16 ----
#pragma unroll
        for (int ks = 0; ks < 2; ++ks) {
            bf16x8 pf;
#pragma unroll
            for (int j = 0; j < 8; ++j)
                pf[j] = f2bf(sP[cur][ks * 16 + hi * 8 + j][wid * 32 + col]);  // conflict-free: 2 rows x 32 consecutive
#pragma unroll
            for (int nt = 0; nt < NT_TILES; ++nt) {
                bf16x8 cf = *(const bf16x8*)&sC[cur][ks * NT_TILES + nt][lane * 8];
                acc[nt] = __builtin_amdgcn_mfma_f32_32x32x16_bf16(pf, cf, acc[nt], 0, 0, 0);
            }
        }
        __syncthreads();
    }

    // ---- epilogue. C/D (m74/m101): class = nt*32+col, pixel = (r&3)+8*(r>>2)+4*hi ----
    const float invT = 1.0f / 0.07f;
    float local_sum = 0.f;
    int   local_cnt = 0;
#pragma unroll
    for (int r = 0; r < 16; ++r) {
        const int prow = (r & 3) + 8 * (r >> 2) + 4 * hi;
        const int pixg = pixbase + wid * 32 + prow;
        const int lab  = lut[idx[pixg]];
        const bool valid = (lab != IGNORE_L);

        float m = -1e30f;
#pragma unroll
        for (int nt = 0; nt < NT_TILES; ++nt) {
            int c = nt * 32 + col;
            float v = (c < NUM_CLS) ? acc[nt][r] : -1e30f;
            m = fmaxf(m, v);
        }
#pragma unroll
        for (int o = 16; o >= 1; o >>= 1) m = fmaxf(m, __shfl_xor(m, o));

        float ssum = 0.f, slab = 0.f;
#pragma unroll
        for (int nt = 0; nt < NT_TILES; ++nt) {
            int c = nt * 32 + col;
            if (c < NUM_CLS) {
                float v = acc[nt][r];
                ssum += __expf((v - m) * invT);
                slab += (c == lab) ? v : 0.f;
            }
        }
#pragma unroll
        for (int o = 16; o >= 1; o >>= 1) {
            ssum += __shfl_xor(ssum, o);
            slab += __shfl_xor(slab, o);
        }
        if (col == 0 && valid) {
            local_sum += (m - slab) * invT + __logf(ssum);
            local_cnt += 1;
        }
    }

    // wave(64) reduce -> block -> global atomics
#pragma unroll
    for (int o = 32; o >= 1; o >>= 1) {
        local_sum += __shfl_down(local_sum, o);
        local_cnt += __shfl_down(local_cnt, o);
    }
    __shared__ float sv[4];
    __shared__ int   sc[4];
    if (lane == 0) { sv[wid] = local_sum; sc[wid] = local_cnt; }
    __syncthreads();
    if (threadIdx.x == 0) {
        float tv = sv[0] + sv[1] + sv[2] + sv[3];
        int   tc = sc[0] + sc[1] + sc[2] + sc[3];
        atomicAdd(ws_sum, (double)tv);
        atomicAdd(ws_cnt, (unsigned long long)tc);
    }
}

__global__ void rsl_final(const double* __restrict__ ws_sum,
                          const unsigned long long* __restrict__ ws_cnt,
                          float* __restrict__ out)
{
    if (threadIdx.x == 0) {
        double c = (double)ws_cnt[0];
        out[0] = (float)(ws_sum[0] / (c > 0.0 ? c : 1.0));
    }
}

extern "C" void kernel_launch(void* const* d_in, const int* in_sizes, int n_in,
                              void* d_out, int out_size, void* d_ws, size_t ws_size,
                              hipStream_t stream)
{
    const float* pred = (const float*)d_in[0];   // (4, 512, 256, 256) fp32
    const float* cls  = (const float*)d_in[1];   // (150, 512) fp32
    const int*   idx  = (const int*)d_in[2];     // (4, 1, 256, 256) int32
    const int*   lut  = (const int*)d_in[3];     // (512,) int32
    float* out = (float*)d_out;

    double* wsd = (double*)d_ws;
    unsigned long long* wsc = (unsigned long long*)((char*)d_ws + 8);
    unsigned short* packed = (unsigned short*)((char*)d_ws + 1024);  // 160 KB

    rsl_pack_cls<<<40, 256, 0, stream>>>(cls, packed, wsd, wsc);

    const int total = 4 * HW_DIM;                 // 262144 pixels
    rsl_mfma<<<total / 128, 256, 0, stream>>>(pred, packed, idx, lut, wsd, wsc);
    rsl_final<<<1, 64, 0, stream>>>(wsd, wsc, out);
}

// Round 6
// 131.677 us; speedup vs baseline: 1.0596x; 1.0596x over previous
//
#include <hip/hip_runtime.h>
#include <hip/hip_bf16.h>

// RelativeSemanticLoss via bf16 MFMA GEMM + fused softmax-NLL epilogue.
// R6: exact R4 structure (16x16x32 MFMA, async global_load_lds dbuf) with
// ONE change: __launch_bounds__(256,3) -> 3 blocks/CU to cover barrier-drain.

#define NUM_CLS 150
#define NT_TILES 10      // 160 padded classes
#define D_DIM   512
#define HW_DIM  65536
#define IGNORE_L 255

typedef __attribute__((ext_vector_type(8))) short bf16x8;
typedef __attribute__((ext_vector_type(4))) float f32x4;
typedef __attribute__((ext_vector_type(4))) unsigned int u32x4;

// async 16B/lane global->LDS: lds dest is WAVE-UNIFORM base (+lane*16 in HW),
// global src is per-lane (m104/m108).
#define GLOAD16(gsrc, ldst) \
    __builtin_amdgcn_global_load_lds((const __attribute__((address_space(1))) void*)(gsrc), \
                                     (__attribute__((address_space(3))) void*)(ldst), 16, 0, 0)

static __device__ __forceinline__ short f2bf(float f) {
    __hip_bfloat16 h = __float2bfloat16(f);   // RNE
    return __builtin_bit_cast(short, h);
}

// Pack cls (150x512 fp32) -> bf16 fragments in lane-linear order:
// packed[(s*10+nt)*512 + l*8 + j] (ushort) = bf16(cls[nt*16+(l&15)][s*32+(l>>4)*8+j])
// Also zeroes the ws accumulators.
__global__ void rsl_pack_cls(const float* __restrict__ cls,
                             unsigned short* __restrict__ packed,
                             double* __restrict__ ws_sum,
                             unsigned long long* __restrict__ ws_cnt)
{
    int t = blockIdx.x * 256 + threadIdx.x;      // 0 .. 16*10*64-1
    if (t == 0) { ws_sum[0] = 0.0; ws_cnt[0] = 0ull; }
    if (t >= 16 * NT_TILES * 64) return;
    int s  = t / (NT_TILES * 64);
    int r  = t - s * (NT_TILES * 64);
    int nt = r >> 6;
    int l  = r & 63;
    int c  = nt * 16 + (l & 15);
    int k  = s * 32 + (l >> 4) * 8;
    unsigned short v[8];
#pragma unroll
    for (int j = 0; j < 8; ++j)
        v[j] = (c < NUM_CLS) ? (unsigned short)f2bf(cls[c * D_DIM + k + j]) : (unsigned short)0;
    u32x4 w;
#pragma unroll
    for (int q = 0; q < 4; ++q)
        w[q] = (unsigned int)v[2 * q] | ((unsigned int)v[2 * q + 1] << 16);
    *(u32x4*)(packed + (size_t)(s * NT_TILES + nt) * 512 + (size_t)l * 8) = w;
}

__global__ __launch_bounds__(256, 3)
void rsl_mfma(const float* __restrict__ pred,
              const unsigned short* __restrict__ packed,
              const int*   __restrict__ idx,
              const int*   __restrict__ lut,
              double* __restrict__ ws_sum,
              unsigned long long* __restrict__ ws_cnt)
{
    // LDS: pred tile [32 dims][128 pixels] fp32 (16KB) x2 + cls tile 10KB x2 = 52KB
    __shared__ float          sP[2][32][128];
    __shared__ unsigned short sC[2][NT_TILES][512];

    const int lane = threadIdx.x & 63;
    const int wid  = threadIdx.x >> 6;
    const int row  = lane & 15;      // M-idx in tile (A frag) / N-idx (C/D)
    const int g    = lane >> 4;      // k-group (A frag) / row-group (C/D)

    const int pixbase = blockIdx.x * 128;            // never straddles b (65536%128==0)
    const int b  = pixbase >> 16;
    const int p0 = pixbase & 0xFFFF;
    // staging: lane covers dim-offset (lane>>5), pixels (lane&31)*4 .. +3 (16B)
    const float* pstage = pred + (size_t)b * D_DIM * HW_DIM
                        + (size_t)(lane >> 5) * HW_DIM + (p0 + (lane & 31) * 4);

    f32x4 acc[2][NT_TILES] = {};

    // ---- prologue: stage s=0 ----
    {
#pragma unroll
        for (int tt = 0; tt < 4; ++tt) {
            const int t = wid * 4 + tt;              // dim pair index 0..15
            GLOAD16(pstage + (size_t)(2 * t) * HW_DIM, &sP[0][2 * t][0]);
        }
        for (int nt = wid; nt < NT_TILES; nt += 4)
            GLOAD16(packed + (size_t)nt * 512 + (size_t)lane * 8, &sC[0][nt][0]);
    }
    __syncthreads();

    for (int s = 0; s < 16; ++s) {
        const int cur = s & 1;
        // ---- stage s+1 into the other buffer (async) ----
        if (s < 15) {
            const float* srcb = pstage + (size_t)((s + 1) * 32) * HW_DIM;
#pragma unroll
            for (int tt = 0; tt < 4; ++tt) {
                const int t = wid * 4 + tt;
                GLOAD16(srcb + (size_t)(2 * t) * HW_DIM, &sP[cur ^ 1][2 * t][0]);
            }
            const unsigned short* csrc = packed + (size_t)((s + 1) * NT_TILES) * 512 + (size_t)lane * 8;
            for (int nt = wid; nt < NT_TILES; nt += 4)
                GLOAD16(csrc + (size_t)nt * 512, &sC[cur ^ 1][nt][0]);
        }

        // ---- compute on current buffer ----
        bf16x8 pf[2];
#pragma unroll
        for (int mt = 0; mt < 2; ++mt)
#pragma unroll
            for (int j = 0; j < 8; ++j)
                pf[mt][j] = f2bf(sP[cur][g * 8 + j][wid * 32 + mt * 16 + row]);

#pragma unroll
        for (int nt = 0; nt < NT_TILES; ++nt) {
            bf16x8 cf = *(const bf16x8*)&sC[cur][nt][lane * 8];
#pragma unroll
            for (int mt = 0; mt < 2; ++mt)
                acc[mt][nt] = __builtin_amdgcn_mfma_f32_16x16x32_bf16(pf[mt], cf, acc[mt][nt], 0, 0, 0);
        }
        __syncthreads();   // drain (vmcnt0+lgkm0) + barrier: next tile ready, buffers safe
    }

    // ---- epilogue. C/D: class = nt*16 + row, pixel = wid*32 + mt*16 + g*4 + j ----
    const float invT = 1.0f / 0.07f;
    float local_sum = 0.f;
    int   local_cnt = 0;
#pragma unroll
    for (int mt = 0; mt < 2; ++mt) {
#pragma unroll
        for (int j = 0; j < 4; ++j) {
            const int pixg = pixbase + wid * 32 + mt * 16 + g * 4 + j;
            const int lab  = lut[idx[pixg]];
            const bool valid = (lab != IGNORE_L);

            float m = -1e30f;
#pragma unroll
            for (int nt = 0; nt < NT_TILES; ++nt) {
                int c = nt * 16 + row;
                float v = (c < NUM_CLS) ? acc[mt][nt][j] : -1e30f;
                m = fmaxf(m, v);
            }
#pragma unroll
            for (int o = 8; o >= 1; o >>= 1) m = fmaxf(m, __shfl_xor(m, o));

            float ssum = 0.f, slab = 0.f;
#pragma unroll
            for (int nt = 0; nt < NT_TILES; ++nt) {
                int c = nt * 16 + row;
                if (c < NUM_CLS) {
                    float v = acc[mt][nt][j];
                    ssum += __expf((v - m) * invT);
                    slab += (c == lab) ? v : 0.f;
                }
            }
#pragma unroll
            for (int o = 8; o >= 1; o >>= 1) {
                ssum += __shfl_xor(ssum, o);
                slab += __shfl_xor(slab, o);
            }
            if (row == 0 && valid) {
                local_sum += (m - slab) * invT + __logf(ssum);
                local_cnt += 1;
            }
        }
    }

    // wave(64) reduce -> block -> global atomics
#pragma unroll
    for (int o = 32; o >= 1; o >>= 1) {
        local_sum += __shfl_down(local_sum, o);
        local_cnt += __shfl_down(local_cnt, o);
    }
    __shared__ float sv[4];
    __shared__ int   sc[4];
    if (lane == 0) { sv[wid] = local_sum; sc[wid] = local_cnt; }
    __syncthreads();
    if (threadIdx.x == 0) {
        float tv = sv[0] + sv[1] + sv[2] + sv[3];
        int   tc = sc[0] + sc[1] + sc[2] + sc[3];
        atomicAdd(ws_sum, (double)tv);
        atomicAdd(ws_cnt, (unsigned long long)tc);
    }
}

__global__ void rsl_final(const double* __restrict__ ws_sum,
                          const unsigned long long* __restrict__ ws_cnt,
                          float* __restrict__ out)
{
    if (threadIdx.x == 0) {
        double c = (double)ws_cnt[0];
        out[0] = (float)(ws_sum[0] / (c > 0.0 ? c : 1.0));
    }
}

extern "C" void kernel_launch(void* const* d_in, const int* in_sizes, int n_in,
                              void* d_out, int out_size, void* d_ws, size_t ws_size,
                              hipStream_t stream)
{
    const float* pred = (const float*)d_in[0];   // (4, 512, 256, 256) fp32
    const float* cls  = (const float*)d_in[1];   // (150, 512) fp32
    const int*   idx  = (const int*)d_in[2];     // (4, 1, 256, 256) int32
    const int*   lut  = (const int*)d_in[3];     // (512,) int32
    float* out = (float*)d_out;

    double* wsd = (double*)d_ws;
    unsigned long long* wsc = (unsigned long long*)((char*)d_ws + 8);
    unsigned short* packed = (unsigned short*)((char*)d_ws + 1024);  // 160 KB

    rsl_pack_cls<<<40, 256, 0, stream>>>(cls, packed, wsd, wsc);

    const int total = 4 * HW_DIM;                 // 262144 pixels
    rsl_mfma<<<total / 128, 256, 0, stream>>>(pred, packed, idx, lut, wsd, wsc);
    rsl_final<<<1, 64, 0, stream>>>(wsd, wsc, out);
}